// Round 2
// baseline (272.924 us; speedup 1.0000x reference)
//
#include <hip/hip_runtime.h>
#include <hip/hip_bf16.h>

typedef short short8 __attribute__((ext_vector_type(8)));
typedef float f32x4 __attribute__((ext_vector_type(4)));

#define EPSF 1e-8f

__device__ __forceinline__ unsigned short f2bf(float f) {
  __hip_bfloat16 h = __float2bfloat16(f);
  return *reinterpret_cast<unsigned short*>(&h);
}

// ---------------------------------------------------------------------------
// prep: per-row chunk norms, global caption l2norm, bf16 convert,
//       pre-swizzled store of Ahat/Bhat (16384 x 128 bf16, rows of 256B with
//       16B-slot XOR swizzle: slot ^= (hatrow & 7)), plus 256-path scale
//       factors fa_e/fa_o (img) and fb_e/fb_o (cap): n128[2v]/n256[v] etc.
// ---------------------------------------------------------------------------
__global__ __launch_bounds__(256) void prep_kernel(
    const float* __restrict__ img, const float* __restrict__ cap,
    unsigned short* __restrict__ Ahat, unsigned short* __restrict__ Bhat,
    float* __restrict__ fa_e, float* __restrict__ fa_o,
    float* __restrict__ fb_e, float* __restrict__ fb_o)
{
  int tid = threadIdx.x;
  int row = blockIdx.x & 2047;
  int isCap = blockIdx.x >> 11;
  const float* src = isCap ? cap : img;
  unsigned short* dstHat = isCap ? Bhat : Ahat;

  // thread t owns elements 4t..4t+3 (all inside 128-chunk j = t>>5)
  float4 v = reinterpret_cast<const float4*>(src + (size_t)row * 1024)[tid];
  float ss = v.x * v.x + v.y * v.y + v.z * v.z + v.w * v.w;
  // reduce within 32-lane group -> per-128-chunk sum of squares
  ss += __shfl_xor(ss, 1);
  ss += __shfl_xor(ss, 2);
  ss += __shfl_xor(ss, 4);
  ss += __shfl_xor(ss, 8);
  ss += __shfl_xor(ss, 16);
  float s128 = ss;
  float s256 = s128 + __shfl_xor(s128, 32);  // 256-chunk sumsq (wave total)

  __shared__ float wsum[4];
  if ((tid & 63) == 0) wsum[tid >> 6] = s256;
  __syncthreads();
  float rowsum = wsum[0] + wsum[1] + wsum[2] + wsum[3];
  float rn = sqrtf(rowsum) + EPSF;  // global caption row norm (+eps)

  // store value = element / (128-block norm of the (possibly row-normed) data)
  // img:  x / (sqrt(s128)+eps)
  // cap:  (x/rn) / (sqrt(s128)/rn + eps) = x / (sqrt(s128) + eps*rn)
  float scale;
  if (isCap) scale = 1.0f / (sqrtf(s128) + EPSF * rn);
  else       scale = 1.0f / (sqrtf(s128) + EPSF);

  unsigned int lo = (unsigned int)f2bf(v.x * scale) | ((unsigned int)f2bf(v.y * scale) << 16);
  unsigned int hi = (unsigned int)f2bf(v.z * scale) | ((unsigned int)f2bf(v.w * scale) << 16);

  int j = tid >> 5;             // 128-chunk index 0..7  (== hatrow & 7)
  int rh = row * 8 + j;         // hat row
  int slot = (tid & 31) >> 1;   // 16B slot 0..15 within the 256B row
  int swz = slot ^ j;           // pre-swizzle so linear LDS staging is conflict-free
  uint2* p = reinterpret_cast<uint2*>(
      (char*)dstHat + (size_t)rh * 256 + (swz << 4) + ((tid & 1) << 3));
  *p = make_uint2(lo, hi);

  int l63 = tid & 63;
  if (l63 == 0 || l63 == 32) {
    // lane 0 holds even chunk (2v), lane 32 odd chunk (2v+1) of this wave's pair
    float n128, n256;
    if (isCap) { n128 = sqrtf(s128) / rn + EPSF; n256 = sqrtf(s256) / rn + EPSF; }
    else       { n128 = sqrtf(s128) + EPSF;      n256 = sqrtf(s256) + EPSF; }
    float f = n128 / n256;
    int v256 = tid >> 6;        // wave index == 256-chunk index
    float* dst;
    if (l63 == 0) dst = isCap ? fb_e : fa_e;
    else          dst = isCap ? fb_o : fa_o;
    dst[row * 4 + v256] = f;
  }
}

// ---------------------------------------------------------------------------
// sims: 128x128 hat-tile GEMM (K=128, bf16 MFMA 16x16x32) + fused epilogue.
// Each block: 16x16 (img,cap) pairs. 4 waves, each a 64x64 hat sub-tile.
// Epilogue entirely in-register via shuffles (C layout: col=lane&15,
// row=(lane>>4)*4+reg), staged to 1KB LDS for coalesced output.
// ---------------------------------------------------------------------------
__global__ __launch_bounds__(256) void sims_kernel(
    const unsigned short* __restrict__ Ahat, const unsigned short* __restrict__ Bhat,
    const float* __restrict__ fa_e, const float* __restrict__ fa_o,
    const float* __restrict__ fb_e, const float* __restrict__ fb_o,
    float* __restrict__ out)
{
  __shared__ char lds[65536];
  int tid = threadIdx.x;
  int lane = tid & 63;
  int w = tid >> 6;

  // bijective XCD swizzle (16384 % 8 == 0)
  int bx = blockIdx.x;
  int swzb = (bx & 7) * 2048 + (bx >> 3);
  int tm = swzb >> 7;
  int tn = swzb & 127;
  int m0 = tm * 128;  // hat row base
  int n0 = tn * 128;  // hat col base

  const char* Ag = (const char*)Ahat + (size_t)m0 * 256;  // contiguous 32KB panel
  const char* Bg = (const char*)Bhat + (size_t)n0 * 256;
  char* ldsA = lds;
  char* ldsB = lds + 32768;

  // stage both panels: per wave 8KB each, width-16 global_load_lds
#pragma unroll
  for (int it = 0; it < 8; ++it) {
    int off = w * 8192 + it * 1024;
    __builtin_amdgcn_global_load_lds(
        (const __attribute__((address_space(1))) void*)(Ag + off + lane * 16),
        (__attribute__((address_space(3))) void*)(ldsA + off), 16, 0, 0);
    __builtin_amdgcn_global_load_lds(
        (const __attribute__((address_space(1))) void*)(Bg + off + lane * 16),
        (__attribute__((address_space(3))) void*)(ldsB + off), 16, 0, 0);
  }
  __syncthreads();

  int wr = (w >> 1) * 64;  // wave's hat-row offset in tile
  int wc = (w & 1) * 64;   // wave's hat-col offset in tile
  int rl = lane & 15;
  int g = lane >> 4;

  f32x4 acc[4][4] = {};

#pragma unroll
  for (int kt = 0; kt < 4; ++kt) {
    // lane reads 16B = 8 bf16 at k = kt*32 + g*8, row = ... + rl
    // byte offset = kt*64 + g*16 -> 16B slot = kt*4 + g
    // swizzled slot = (kt*4+g) ^ (row & 7); (row&7)==(rl&7)
    int sw = (((kt << 2) + g) ^ (rl & 7)) << 4;
    short8 av[4], bv[4];
#pragma unroll
    for (int f = 0; f < 4; ++f) {
      av[f] = *reinterpret_cast<const short8*>(ldsA + (wr + f * 16 + rl) * 256 + sw);
      bv[f] = *reinterpret_cast<const short8*>(ldsB + (wc + f * 16 + rl) * 256 + sw);
    }
#pragma unroll
    for (int fm = 0; fm < 4; ++fm)
#pragma unroll
      for (int fn = 0; fn < 4; ++fn)
        acc[fm][fn] = __builtin_amdgcn_mfma_f32_16x16x32_bf16(av[fm], bv[fn], acc[fm][fn], 0, 0, 0);
  }

  __syncthreads();  // all tile ds_reads done -> safe to reuse LDS for output
  float* outLds = (float*)lds;

  // per-lane caption-side 256-path factors (one per fragment column)
  float fbe[4], fbo[4];
  int colBase = n0 + wc + rl;
#pragma unroll
  for (int fn = 0; fn < 4; ++fn) {
    int nb = (colBase + fn * 16) >> 1;
    fbe[fn] = fb_e[nb];
    fbo[fn] = fb_o[nb];
  }

  bool writer = ((lane & 7) == 0) && ((g & 1) == 0);

#pragma unroll
  for (int fm = 0; fm < 4; ++fm) {
    int rBase = m0 + wr + fm * 16 + 4 * g;  // lane's first hat row (even)
    int vi = rBase >> 1;
    float fae0 = fa_e[vi], fao0 = fa_o[vi];
    float fae1 = fa_e[vi + 1], fao1 = fa_o[vi + 1];
#pragma unroll
    for (int fn = 0; fn < 4; ++fn) {
      f32x4 a = acc[fm][fn];

      // ---- 128-path: sum_t max_v P (P already fully normalized) ----
      float mm = fmaxf(fmaxf(a[0], a[1]), fmaxf(a[2], a[3]));  // max over lane's 4 rows
      mm = fmaxf(mm, __shfl_xor(mm, 16));                      // + other 4 rows of the 8
      float y = mm;
      y += __shfl_xor(y, 1);
      y += __shfl_xor(y, 2);
      y += __shfl_xor(y, 4);                                   // sum over 8 cols (t)

      // ---- 256-path: Q[v][t] = fe*P[2v][2t] + fo*P[2v+1][2t+1] ----
      float s1 = __shfl_xor(a[1], 1);  // P[odd row][odd col] partner (valid on even lanes)
      float s3 = __shfl_xor(a[3], 1);
      float qa = a[0] * (fae0 * fbe[fn]) + s1 * (fao0 * fbo[fn]);  // v = vi-rel 0
      float qb = a[2] * (fae1 * fbe[fn]) + s3 * (fao1 * fbo[fn]);  // v = vi-rel 1
      float qm = fmaxf(qa, qb);
      qm = fmaxf(qm, __shfl_xor(qm, 16));  // max over all 4 v (even-lane parity preserved)
      float z = qm;
      z += __shfl_xor(z, 2);
      z += __shfl_xor(z, 4);               // sum over 4 t (even lanes closed under xor 2,4)

      if (writer) {
        int pi = (wr >> 3) + fm * 2 + (g >> 1);
        int pj = (wc >> 3) + fn * 2 + (rl >> 3);
        outLds[pi * 16 + pj] = y + z;
      }
    }
  }

  __syncthreads();
  int pr = tid >> 4, pc = tid & 15;
  out[(size_t)(tm * 16 + pr) * 2048 + (tn * 16 + pc)] = outLds[tid];
}

// ---------------------------------------------------------------------------
extern "C" void kernel_launch(void* const* d_in, const int* in_sizes, int n_in,
                              void* d_out, int out_size, void* d_ws, size_t ws_size,
                              hipStream_t stream) {
  const float* img = (const float*)d_in[0];
  const float* cap = (const float*)d_in[1];
  float* out = (float*)d_out;

  char* ws = (char*)d_ws;
  unsigned short* Ahat = (unsigned short*)ws;                          // 4 MB
  unsigned short* Bhat = (unsigned short*)(ws + (size_t)4 * 1024 * 1024);  // 4 MB
  float* fa_e = (float*)(ws + (size_t)8 * 1024 * 1024);  // 8192 f32 each
  float* fa_o = fa_e + 8192;
  float* fb_e = fa_o + 8192;
  float* fb_o = fb_e + 8192;

  prep_kernel<<<4096, 256, 0, stream>>>(img, cap, Ahat, Bhat, fa_e, fa_o, fb_e, fb_o);
  sims_kernel<<<16384, 256, 0, stream>>>(Ahat, Bhat, fa_e, fa_o, fb_e, fb_o, out);
}

// Round 3
// 186.619 us; speedup vs baseline: 1.4625x; 1.4625x over previous
//
#include <hip/hip_runtime.h>
#include <hip/hip_bf16.h>

typedef short short8 __attribute__((ext_vector_type(8)));
typedef float f32x4 __attribute__((ext_vector_type(4)));

#define EPSF 1e-8f
#define NROWS 16384  // total hat rows (2048 rows * 8 chunks)

__device__ __forceinline__ unsigned short f2bf(float f) {
  __hip_bfloat16 h = __float2bfloat16(f);
  return *reinterpret_cast<unsigned short*>(&h);
}

// DPP cross-lane (VALU, no LDS): returns lane's partner value per CTRL.
template <int CTRL>
__device__ __forceinline__ float dppf(float x) {
  return __builtin_bit_cast(
      float, __builtin_amdgcn_update_dpp(0, __builtin_bit_cast(int, x), CTRL,
                                         0xF, 0xF, true));
}
#define DPP_XOR1 0xB1   // quad_perm(1,0,3,2)
#define DPP_XOR2 0x4E   // quad_perm(2,3,0,1)
#define DPP_P4 0x12C    // row_ror:12 -> lane i gets lane (i+4)&15

// lane ^ 16 via ds_swizzle BitMode (and=0x1F, xor=16)
__device__ __forceinline__ float swz16(float x) {
  return __builtin_bit_cast(
      float, __builtin_amdgcn_ds_swizzle(__builtin_bit_cast(int, x), 0x401F));
}

// ---------------------------------------------------------------------------
// prep: per-row chunk norms, global caption l2norm, bf16 convert, K-MAJOR
// store of Ahat/Bhat: byte addr = (slot*NROWS + hatrow)*16, slot = 16B of K.
// This makes sims' fragment loads contiguous 256B global reads (no LDS).
// Also writes 256-path factors fa_e/fa_o (img), fb_e/fb_o (cap).
// ---------------------------------------------------------------------------
__global__ __launch_bounds__(256) void prep_kernel(
    const float* __restrict__ img, const float* __restrict__ cap,
    unsigned short* __restrict__ Ahat, unsigned short* __restrict__ Bhat,
    float* __restrict__ fa_e, float* __restrict__ fa_o,
    float* __restrict__ fb_e, float* __restrict__ fb_o)
{
  int tid = threadIdx.x;
  int row = blockIdx.x & 2047;
  int isCap = blockIdx.x >> 11;
  const float* src = isCap ? cap : img;
  unsigned short* dstHat = isCap ? Bhat : Ahat;

  // thread t owns elements 4t..4t+3 (inside 128-chunk j = t>>5)
  float4 v = reinterpret_cast<const float4*>(src + (size_t)row * 1024)[tid];
  float ss = v.x * v.x + v.y * v.y + v.z * v.z + v.w * v.w;
  ss += __shfl_xor(ss, 1);
  ss += __shfl_xor(ss, 2);
  ss += __shfl_xor(ss, 4);
  ss += __shfl_xor(ss, 8);
  ss += __shfl_xor(ss, 16);
  float s128 = ss;
  float s256 = s128 + __shfl_xor(s128, 32);

  __shared__ float wsum[4];
  if ((tid & 63) == 0) wsum[tid >> 6] = s256;
  __syncthreads();
  float rowsum = wsum[0] + wsum[1] + wsum[2] + wsum[3];
  float rn = sqrtf(rowsum) + EPSF;  // global caption row norm (+eps)

  // img:  x / (sqrt(s128)+eps)
  // cap:  (x/rn) / (sqrt(s128)/rn + eps) = x / (sqrt(s128) + eps*rn)
  float scale;
  if (isCap) scale = 1.0f / (sqrtf(s128) + EPSF * rn);
  else       scale = 1.0f / (sqrtf(s128) + EPSF);

  unsigned int lo = (unsigned int)f2bf(v.x * scale) | ((unsigned int)f2bf(v.y * scale) << 16);
  unsigned int hi = (unsigned int)f2bf(v.z * scale) | ((unsigned int)f2bf(v.w * scale) << 16);

  int j = tid >> 5;            // 128-chunk index 0..7
  int rh = row * 8 + j;        // hat row
  int s = (tid & 31) >> 1;     // 16B k-slot 0..15
  uint2* p = reinterpret_cast<uint2*>(
      (char*)dstHat + ((size_t)s * NROWS + rh) * 16 + ((tid & 1) << 3));
  *p = make_uint2(lo, hi);

  int l63 = tid & 63;
  if (l63 == 0 || l63 == 32) {
    float n128, n256;
    if (isCap) { n128 = sqrtf(s128) / rn + EPSF; n256 = sqrtf(s256) / rn + EPSF; }
    else       { n128 = sqrtf(s128) + EPSF;      n256 = sqrtf(s256) + EPSF; }
    float f = n128 / n256;
    int v256 = tid >> 6;
    float* dst;
    if (l63 == 0) dst = isCap ? fb_e : fa_e;
    else          dst = isCap ? fb_o : fa_o;
    dst[row * 4 + v256] = f;
  }
}

// ---------------------------------------------------------------------------
// sims: 128x128 hat-tile GEMM (K=128, bf16 MFMA 16x16x32), fragments loaded
// DIRECTLY from K-major global (contiguous 256B per 16-lane group; no LDS
// staging, no barriers in the main path). Fused epilogue in-register via
// DPP (xor1/xor2/+4) + ds_swizzle (xor16); 1KB LDS only for output staging.
// C layout: col=lane&15, row=(lane>>4)*4+reg.
// ---------------------------------------------------------------------------
__global__ __launch_bounds__(256) void sims_kernel(
    const unsigned short* __restrict__ Ahat, const unsigned short* __restrict__ Bhat,
    const float* __restrict__ fa_e, const float* __restrict__ fa_o,
    const float* __restrict__ fb_e, const float* __restrict__ fb_o,
    float* __restrict__ out)
{
  __shared__ float outLds[256];
  int tid = threadIdx.x;
  int lane = tid & 63;
  int w = tid >> 6;

  // XCD-partitioned mapping: XCD x owns tn strip [16x,16x+16); within an XCD,
  // 16 consecutive blocks share tm (A panel L2-reuse). Bijective.
  int bx = blockIdx.x;
  int x = bx & 7;
  int l = bx >> 3;           // 0..2047
  int tm = l >> 4;           // 0..127
  int tn = (x << 4) | (l & 15);
  int m0 = tm * 128;
  int n0 = tn * 128;

  int wr = (w >> 1) * 64;  // wave's hat-row offset in tile
  int wc = (w & 1) * 64;   // wave's hat-col offset in tile
  int rl = lane & 15;
  int g = lane >> 4;

  const char* Ab = (const char*)Ahat;
  const char* Bb = (const char*)Bhat;

  f32x4 acc[4][4] = {};

#pragma unroll
  for (int kt = 0; kt < 4; ++kt) {
    int s = kt * 4 + g;  // 16B k-slot this lane reads
    const char* As = Ab + ((size_t)s * NROWS + m0 + wr + rl) * 16;
    const char* Bs = Bb + ((size_t)s * NROWS + n0 + wc + rl) * 16;
    short8 av[4], bv[4];
#pragma unroll
    for (int f = 0; f < 4; ++f) {
      av[f] = *reinterpret_cast<const short8*>(As + f * (16 * 16));
      bv[f] = *reinterpret_cast<const short8*>(Bs + f * (16 * 16));
    }
#pragma unroll
    for (int fm = 0; fm < 4; ++fm)
#pragma unroll
      for (int fn = 0; fn < 4; ++fn)
        acc[fm][fn] = __builtin_amdgcn_mfma_f32_16x16x32_bf16(av[fm], bv[fn], acc[fm][fn], 0, 0, 0);
  }

  // per-lane caption-side 256-path factors (one per fragment column)
  float fbe[4], fbo[4];
  int colBase = n0 + wc + rl;
#pragma unroll
  for (int fn = 0; fn < 4; ++fn) {
    int nb = (colBase + fn * 16) >> 1;
    fbe[fn] = fb_e[nb];
    fbo[fn] = fb_o[nb];
  }

  bool writer = ((lane & 7) == 0) && ((g & 1) == 0);

#pragma unroll
  for (int fm = 0; fm < 4; ++fm) {
    int rBase = m0 + wr + fm * 16 + 4 * g;  // lane's first hat row (even)
    int vi = rBase >> 1;
    float fae0 = fa_e[vi], fao0 = fa_o[vi];
    float fae1 = fa_e[vi + 1], fao1 = fa_o[vi + 1];
#pragma unroll
    for (int fn = 0; fn < 4; ++fn) {
      f32x4 a = acc[fm][fn];

      // ---- 128-path: sum_t max_v P ----
      float mm = fmaxf(fmaxf(a[0], a[1]), fmaxf(a[2], a[3]));  // max over 4 rows
      mm = fmaxf(mm, swz16(mm));                               // + other 4 of the 8
      float y = mm;
      y += dppf<DPP_XOR1>(y);
      y += dppf<DPP_XOR2>(y);
      y += dppf<DPP_P4>(y);  // sum over the 8 cols of this cap row

      // ---- 256-path: Q[v][t] = fe*P[2v][2t] + fo*P[2v+1][2t+1] ----
      float s1 = dppf<DPP_XOR1>(a[1]);  // odd-row value at odd col -> even lane
      float s3 = dppf<DPP_XOR1>(a[3]);
      float qa = a[0] * (fae0 * fbe[fn]) + s1 * (fao0 * fbo[fn]);
      float qb = a[2] * (fae1 * fbe[fn]) + s3 * (fao1 * fbo[fn]);
      float qm = fmaxf(qa, qb);
      qm = fmaxf(qm, swz16(qm));  // max over all 4 v
      float z = qm;
      z += dppf<DPP_XOR2>(z);
      z += dppf<DPP_P4>(z);       // sum over 4 t (valid at lanes 0 mod 8)

      if (writer) {
        int pi = (wr >> 3) + fm * 2 + (g >> 1);
        int pj = (wc >> 3) + fn * 2 + (rl >> 3);
        outLds[pi * 16 + pj] = y + z;
      }
    }
  }

  __syncthreads();
  int pr = tid >> 4, pc = tid & 15;
  out[(size_t)(tm * 16 + pr) * 2048 + (tn * 16 + pc)] = outLds[tid];
}

// ---------------------------------------------------------------------------
extern "C" void kernel_launch(void* const* d_in, const int* in_sizes, int n_in,
                              void* d_out, int out_size, void* d_ws, size_t ws_size,
                              hipStream_t stream) {
  const float* img = (const float*)d_in[0];
  const float* cap = (const float*)d_in[1];
  float* out = (float*)d_out;

  char* ws = (char*)d_ws;
  unsigned short* Ahat = (unsigned short*)ws;                              // 4 MB, K-major
  unsigned short* Bhat = (unsigned short*)(ws + (size_t)4 * 1024 * 1024);  // 4 MB, K-major
  float* fa_e = (float*)(ws + (size_t)8 * 1024 * 1024);
  float* fa_o = fa_e + 8192;
  float* fb_e = fa_o + 8192;
  float* fb_o = fb_e + 8192;

  prep_kernel<<<4096, 256, 0, stream>>>(img, cap, Ahat, Bhat, fa_e, fa_o, fb_e, fb_o);
  sims_kernel<<<16384, 256, 0, stream>>>(Ahat, Bhat, fa_e, fa_o, fb_e, fb_o, out);
}

// Round 4
// 166.091 us; speedup vs baseline: 1.6432x; 1.1236x over previous
//
#include <hip/hip_runtime.h>
#include <hip/hip_bf16.h>

typedef short short8 __attribute__((ext_vector_type(8)));
typedef float f32x4 __attribute__((ext_vector_type(4)));

#define EPSF 1e-8f
#define NROWS 16384  // total hat rows (2048 rows * 8 chunks)

__device__ __forceinline__ unsigned short f2bf(float f) {
  __hip_bfloat16 h = __float2bfloat16(f);
  return *reinterpret_cast<unsigned short*>(&h);
}

// DPP mov with old=undef -> GCNDPPCombine can fuse into the consuming VALU op.
template <int CTRL>
__device__ __forceinline__ float dmov(float x) {
  return __builtin_bit_cast(
      float, __builtin_amdgcn_mov_dpp(__builtin_bit_cast(int, x), CTRL, 0xF, 0xF, false));
}
#define DPP_XOR1 0xB1   // quad_perm(1,0,3,2)
#define DPP_XOR2 0x4E   // quad_perm(2,3,0,1)
#define DPP_P4 0x12C    // row_ror:12 -> lane i gets lane (i+4)&15 (verified passing r3)

// lane ^ 16 via ds_swizzle BitMode (and=0x1F, xor=16)
__device__ __forceinline__ float swz16(float x) {
  return __builtin_bit_cast(
      float, __builtin_amdgcn_ds_swizzle(__builtin_bit_cast(int, x), 0x401F));
}

// ---------------------------------------------------------------------------
// prep: per-row chunk norms, global caption l2norm, bf16 convert, K-MAJOR
// store of Ahat/Bhat: byte addr = (slot*NROWS + hatrow)*16.  Stores go through
// a small LDS transpose so each global store instr covers 4x128B streams
// instead of 32x16B scatter.  Factors stored interleaved: f[(row*4+v)*2+{e,o}].
// ---------------------------------------------------------------------------
__global__ __launch_bounds__(256) void prep_kernel(
    const float* __restrict__ img, const float* __restrict__ cap,
    unsigned short* __restrict__ Ahat, unsigned short* __restrict__ Bhat,
    float* __restrict__ fa, float* __restrict__ fb)
{
  __shared__ float wsum[4];
  __shared__ uint2 lds2[16 * 18];  // [slot s][j*2+half], stride 18 to break banks
  int tid = threadIdx.x;
  int row = blockIdx.x & 2047;
  int isCap = blockIdx.x >> 11;
  const float* src = isCap ? cap : img;
  unsigned short* dstHat = isCap ? Bhat : Ahat;

  // thread t owns elements 4t..4t+3 (inside 128-chunk j = t>>5)
  float4 v = reinterpret_cast<const float4*>(src + (size_t)row * 1024)[tid];
  float ss = v.x * v.x + v.y * v.y + v.z * v.z + v.w * v.w;
  ss += __shfl_xor(ss, 1);
  ss += __shfl_xor(ss, 2);
  ss += __shfl_xor(ss, 4);
  ss += __shfl_xor(ss, 8);
  ss += __shfl_xor(ss, 16);
  float s128 = ss;
  float s256 = s128 + __shfl_xor(s128, 32);

  if ((tid & 63) == 0) wsum[tid >> 6] = s256;
  __syncthreads();
  float rowsum = wsum[0] + wsum[1] + wsum[2] + wsum[3];
  float rn = sqrtf(rowsum) + EPSF;  // global caption row norm (+eps)

  // img:  x / (sqrt(s128)+eps);   cap: x / (sqrt(s128) + eps*rn)
  float scale;
  if (isCap) scale = 1.0f / (sqrtf(s128) + EPSF * rn);
  else       scale = 1.0f / (sqrtf(s128) + EPSF);

  unsigned int lo = (unsigned int)f2bf(v.x * scale) | ((unsigned int)f2bf(v.y * scale) << 16);
  unsigned int hi = (unsigned int)f2bf(v.z * scale) | ((unsigned int)f2bf(v.w * scale) << 16);

  int j = tid >> 5;            // 128-chunk index 0..7
  int s = (tid & 31) >> 1;     // 16B k-slot 0..15
  int half = tid & 1;
  lds2[s * 18 + j * 2 + half] = make_uint2(lo, hi);

  int l63 = tid & 63;
  if (l63 == 0 || l63 == 32) {
    float n128, n256;
    if (isCap) { n128 = sqrtf(s128) / rn + EPSF; n256 = sqrtf(s256) / rn + EPSF; }
    else       { n128 = sqrtf(s128) + EPSF;      n256 = sqrtf(s256) + EPSF; }
    float f = n128 / n256;
    int v256 = tid >> 6;
    float* dst = isCap ? fb : fa;
    dst[(row * 4 + v256) * 2 + (l63 == 32 ? 1 : 0)] = f;
  }
  __syncthreads();

  // phase 2: coalesced K-major store (per wave: 4 streams x 128B contiguous)
  int s2 = tid >> 4, j2 = (tid & 15) >> 1, h2 = tid & 1;
  uint2 val = lds2[s2 * 18 + j2 * 2 + h2];
  *reinterpret_cast<uint2*>(
      (char*)dstHat + ((size_t)s2 * NROWS + row * 8 + j2) * 16 + h2 * 8) = val;
}

// ---------------------------------------------------------------------------
// sims: 128x128 hat-tile GEMM (K=128, bf16 MFMA 16x16x32), fragments loaded
// directly from K-major global via saddr-form loads (uniform base + 32-bit
// divergent offset).  Fused epilogue: merged Y+Z reduction tree with
// DPP-fusable movs; 1KB LDS only for output staging.
// C layout: col=lane&15, row=(lane>>4)*4+reg.
// ---------------------------------------------------------------------------
__global__ __launch_bounds__(256, 4) void sims_kernel(
    const unsigned short* __restrict__ Ahat, const unsigned short* __restrict__ Bhat,
    const float* __restrict__ fa, const float* __restrict__ fb,
    float* __restrict__ out)
{
  __shared__ float outLds[256];
  int tid = threadIdx.x;
  int lane = tid & 63;
  int w = tid >> 6;

  // XCD-partitioned mapping: XCD x owns tn strip [16x,16x+16); within an XCD,
  // 16 consecutive blocks share tm (A panel L2-reuse). Bijective.
  int bx = blockIdx.x;
  int x = bx & 7;
  int l = bx >> 3;
  int tm = l >> 4;
  int tn = (x << 4) | (l & 15);
  int m0 = tm * 128;
  int n0 = tn * 128;

  int wr = (w >> 1) * 64;
  int wc = (w & 1) * 64;
  int rl = lane & 15;
  int g = lane >> 4;

  // divergent 32-bit offsets (slot g part folded in); uniform k-step bases
  unsigned vA = (unsigned)g * (NROWS * 16u) + (unsigned)(m0 + wr + rl) * 16u;
  unsigned vB = (unsigned)g * (NROWS * 16u) + (unsigned)(n0 + wc + rl) * 16u;
  const char* Abase = (const char*)Ahat;
  const char* Bbase = (const char*)Bhat;

  // caption-side factors (interleaved e,o): prefetch before the MFMA loop
  float2 fbv[4];
  int colBase = n0 + wc + rl;
#pragma unroll
  for (int fn = 0; fn < 4; ++fn)
    fbv[fn] = *reinterpret_cast<const float2*>(fb + ((colBase + fn * 16) >> 1) * 2);

  f32x4 acc[4][4] = {};

#pragma unroll
  for (int kt = 0; kt < 4; ++kt) {
    const char* Ak = Abase + (size_t)kt * (4u * NROWS * 16u);
    const char* Bk = Bbase + (size_t)kt * (4u * NROWS * 16u);
    short8 av[4], bv[4];
#pragma unroll
    for (int f = 0; f < 4; ++f) {
      av[f] = *reinterpret_cast<const short8*>(Ak + vA + f * 256);
      bv[f] = *reinterpret_cast<const short8*>(Bk + vB + f * 256);
    }
#pragma unroll
    for (int fm = 0; fm < 4; ++fm)
#pragma unroll
      for (int fn = 0; fn < 4; ++fn)
        acc[fm][fn] = __builtin_amdgcn_mfma_f32_16x16x32_bf16(av[fm], bv[fn], acc[fm][fn], 0, 0, 0);
  }

  bool writer = ((lane & 7) == 0) && ((g & 1) == 0);
  int pBase = ((wr >> 3) + (g >> 1)) * 16 + (wc >> 3) + (rl >> 3);

#pragma unroll
  for (int fm = 0; fm < 4; ++fm) {
    int rBase = m0 + wr + fm * 16 + 4 * g;  // lane's first hat row (even)
    int vi = rBase >> 1;
    float4 fav = *reinterpret_cast<const float4*>(fa + vi * 2);  // e0,o0,e1,o1
#pragma unroll
    for (int fn = 0; fn < 4; ++fn) {
      f32x4 a = acc[fm][fn];

      // m8 = max over the 8 hat rows of this img row (per col), all lanes
      float mm = fmaxf(fmaxf(a[0], a[1]), fmaxf(a[2], a[3]));
      float m8 = fmaxf(mm, swz16(mm));
      // u = pair-sum over adjacent cols (valid on even lanes)
      float u = m8 + dmov<DPP_XOR1>(m8);

      // 256-path: Q = fe*P[2v][2t] + fo*P[2v+1][2t+1], rows in-lane, col via xor1
      float s1 = dmov<DPP_XOR1>(a[1]);
      float s3 = dmov<DPP_XOR1>(a[3]);
      float qa = a[0] * (fav.x * fbv[fn].x) + s1 * (fav.y * fbv[fn].y);
      float qb = a[2] * (fav.z * fbv[fn].x) + s3 * (fav.w * fbv[fn].y);
      float qm = fmaxf(qa, qb);
      qm = fmaxf(qm, swz16(qm));  // max over all 4 v of this img row

      // merged tree: sum_{even c} (u + qm) = Y + Z
      float wv = u + qm;
      wv += dmov<DPP_XOR2>(wv);
      wv += dmov<DPP_P4>(wv);

      if (writer) outLds[pBase + fm * 32 + fn * 2] = wv;
    }
  }

  __syncthreads();
  int pr = tid >> 4, pc = tid & 15;
  out[(size_t)(tm * 16 + pr) * 2048 + (tn * 16 + pc)] = outLds[tid];
}

// ---------------------------------------------------------------------------
extern "C" void kernel_launch(void* const* d_in, const int* in_sizes, int n_in,
                              void* d_out, int out_size, void* d_ws, size_t ws_size,
                              hipStream_t stream) {
  const float* img = (const float*)d_in[0];
  const float* cap = (const float*)d_in[1];
  float* out = (float*)d_out;

  char* ws = (char*)d_ws;
  unsigned short* Ahat = (unsigned short*)ws;                              // 4 MB, K-major
  unsigned short* Bhat = (unsigned short*)(ws + (size_t)4 * 1024 * 1024);  // 4 MB, K-major
  float* fa = (float*)(ws + (size_t)8 * 1024 * 1024);  // 2048*4 pairs (e,o)
  float* fb = fa + 2048 * 4 * 2;

  prep_kernel<<<4096, 256, 0, stream>>>(img, cap, Ahat, Bhat, fa, fb);
  sims_kernel<<<16384, 256, 0, stream>>>(Ahat, Bhat, fa, fb, out);
}